// Round 18
// baseline (170.124 us; speedup 1.0000x reference)
//
#include <hip/hip_runtime.h>
#include <hip/hip_bf16.h>
#include <math.h>

typedef __attribute__((ext_vector_type(8))) short s16x8;
typedef __attribute__((ext_vector_type(4))) float f32x4;

#define MFMA16(a,b,c) __builtin_amdgcn_mfma_f32_16x16x32_bf16((a),(b),(c),0,0,0)

#define GLD16(gp, lp) __builtin_amdgcn_global_load_lds( \
  (const __attribute__((address_space(1))) unsigned int*)(gp), \
  (__attribute__((address_space(3))) unsigned int*)(lp), 16, 0, 0)

static __device__ __forceinline__ unsigned short f2bu(float f) {
  __hip_bfloat16 h = __float2bfloat16(f);
  unsigned short u; __builtin_memcpy(&u, &h, 2); return u;
}
static __device__ __forceinline__ float b2f(unsigned short u) {
  unsigned int x = ((unsigned int)u) << 16; float f; __builtin_memcpy(&f, &x, 4); return f;
}
// 2 f32 -> packed bf16 pair in one HW op (lo = s0, hi = s1)
static __device__ __forceinline__ unsigned int cvtpk(float lo, float hi) {
  unsigned int r;
  asm("v_cvt_pk_bf16_f32 %0, %1, %2" : "=v"(r) : "v"(lo), "v"(hi));
  return r;
}

// ---------------------------------------------------------------- cast (exact 1D grid, 32B/thread) + fu/pairmask
__global__ __launch_bounds__(256) void cast_all(const float* __restrict__ q, const float* __restrict__ k,
                                                const float* __restrict__ v,
                                                const float* __restrict__ Wq, const float* __restrict__ Wk,
                                                const float* __restrict__ Wv, const float* __restrict__ Wo,
                                                const int* __restrict__ mask,
                                                unsigned short* __restrict__ qc, unsigned short* __restrict__ kc,
                                                unsigned short* __restrict__ vc,
                                                unsigned short* __restrict__ wq, unsigned short* __restrict__ wk,
                                                unsigned short* __restrict__ wv, unsigned short* __restrict__ wo,
                                                int* __restrict__ fu, unsigned int* __restrict__ pm) {
  const float SCALE2 = 0.125f * 1.4426950408889634f;   // folded into Wq -> QK^T lands in log2 domain
  const int bid = blockIdx.x;
  if (bid < 6144) {
    const int y = bid >> 11;                 // 0,1,2
    const float* in = (y == 0) ? q : (y == 1) ? k : v;
    unsigned short* out = (y == 0) ? qc : (y == 1) ? kc : vc;
    const size_t i = (size_t)(bid & 2047) * 256 + threadIdx.x;  // 8 floats each
    const float4* p = (const float4*)(in + i * 8);
    float4 v0 = p[0], v1 = p[1];
    uint4 pk;
    pk.x = cvtpk(v0.x, v0.y); pk.y = cvtpk(v0.z, v0.w);
    pk.z = cvtpk(v1.x, v1.y); pk.w = cvtpk(v1.z, v1.w);
    *(uint4*)(out + i * 8) = pk;
  } else if (bid < 8192) {
    const int r = bid - 6144;
    const int y = r >> 9;                    // 0..3
    const float scl = (y == 0) ? SCALE2 : 1.0f;
    const float* in = (y == 0) ? Wq : (y == 1) ? Wk : (y == 2) ? Wv : Wo;
    unsigned short* out = (y == 0) ? wq : (y == 1) ? wk : (y == 2) ? wv : wo;
    const size_t i = (size_t)(r & 511) * 256 + threadIdx.x;
    const float4* p = (const float4*)(in + i * 8);
    float4 v0 = p[0], v1 = p[1];
    uint4 pk;
    pk.x = cvtpk(v0.x * scl, v0.y * scl); pk.y = cvtpk(v0.z * scl, v0.w * scl);
    pk.z = cvtpk(v1.x * scl, v1.y * scl); pk.w = cvtpk(v1.z * scl, v1.w * scl);
    *(uint4*)(out + i * 8) = pk;
  } else {
    const int S = 2048;
    const int b = bid - 8192;                // 0,1
    __shared__ int red[256];
    int best = S;
    for (int kk = threadIdx.x; kk < 1024; kk += 256) {
      int m0 = mask[b * S + 2 * kk], m1 = mask[b * S + 2 * kk + 1];
      pm[b * 1024 + kk] = (m0 ? 0xFFFFu : 0u) | (m1 ? 0xFFFF0000u : 0u);
      if (m1) best = min(best, 2 * kk + 1);
      if (m0) best = min(best, 2 * kk);
    }
    red[threadIdx.x] = best;
    __syncthreads();
    for (int s = 128; s > 0; s >>= 1) {
      if (threadIdx.x < s) red[threadIdx.x] = min(red[threadIdx.x], red[threadIdx.x + s]);
      __syncthreads();
    }
    if (threadIdx.x == 0) fu[b] = red[0];
  }
}

// ---------------------------------------------------------------- shared GEMM core: C = A(bf16) * Bw(bf16)^T
static __device__ __forceinline__ void gemm_core(const unsigned short* __restrict__ Aw,
                                                 const unsigned short* __restrict__ Bw,
                                                 int m0, int n0,
                                                 f32x4 (&acc)[4][4],
                                                 unsigned short (*As)[64], unsigned short (*Bs)[64]) {
  const int K = 1024;
  const int tid = threadIdx.x;
  const int lane = tid & 63, wave = tid >> 6;
  const int wm = wave >> 1, wn = wave & 1;
  const int row16 = lane & 15, kgrp = lane >> 4;
  const int srow = lane >> 3, sslot = (lane & 7) ^ srow;
  const int sw = row16 & 7;

  for (int k0 = 0; k0 < K; k0 += 64) {
#pragma unroll
    for (int i = 0; i < 4; i++) {
      int rr = (wave * 4 + i) * 8 + srow;
      GLD16(Aw + (size_t)(m0 + rr) * K + k0 + sslot * 8, (char*)As + (wave * 4 + i) * 1024);
      GLD16(Bw + (size_t)(n0 + rr) * K + k0 + sslot * 8, (char*)Bs + (wave * 4 + i) * 1024);
    }
    __syncthreads();

#pragma unroll
    for (int kk = 0; kk < 2; kk++) {
      s16x8 af[4], bfr[4];
#pragma unroll
      for (int mi = 0; mi < 4; mi++) {
        int rr = wm * 64 + mi * 16 + row16;
        af[mi] = *(const s16x8*)((char*)&As[rr][0] + ((kk * 4 + kgrp) ^ sw) * 16);
      }
#pragma unroll
      for (int ni = 0; ni < 4; ni++) {
        int rr = wn * 64 + ni * 16 + row16;
        bfr[ni] = *(const s16x8*)((char*)&Bs[rr][0] + ((kk * 4 + kgrp) ^ sw) * 16);
      }
#pragma unroll
      for (int mi = 0; mi < 4; mi++)
#pragma unroll
        for (int ni = 0; ni < 4; ni++)
          acc[mi][ni] = MFMA16(af[mi], bfr[ni], acc[mi][ni]);
    }
    __syncthreads();
  }
}

// fused Q/K/V projection, 1D grid 768, XCD-aware. z=2 writes Vt transposed
// (via LDS transpose -> coalesced 16B stores); z<2 scalar stores (L2-absorbed, measured best).
__global__ __launch_bounds__(256) void qkv_gemm(const unsigned short* __restrict__ qc,
                                                const unsigned short* __restrict__ kc,
                                                const unsigned short* __restrict__ vc,
                                                const unsigned short* __restrict__ Wqb,
                                                const unsigned short* __restrict__ Wkb,
                                                const unsigned short* __restrict__ Wvb,
                                                unsigned short* __restrict__ Qb,
                                                unsigned short* __restrict__ Kb,
                                                unsigned short* __restrict__ Vt) {
  __shared__ unsigned short lds[16384];                  // 32 KB: As|Bs during GEMM, T after
  unsigned short (*As)[64] = (unsigned short (*)[64])lds;
  unsigned short (*Bs)[64] = (unsigned short (*)[64])(lds + 8192);
  const int xcd = blockIdx.x & 7, u = blockIdx.x >> 3;   // u 0..95
  const int g = xcd * 12 + (u >> 3);                     // unit 0..95
  const int z = g >> 5, mstrip = g & 31;
  const int m0 = mstrip * 128, n0 = (u & 7) * 128;

  const unsigned short* A = (z == 0) ? qc : (z == 1) ? kc : vc;
  const unsigned short* Bw = (z == 0) ? Wqb : (z == 1) ? Wkb : Wvb;

  f32x4 acc[4][4] = {};
  gemm_core(A, Bw, m0, n0, acc, As, Bs);

  const int tid = threadIdx.x;
  const int lane = tid & 63, wave = tid >> 6;
  const int wm = wave >> 1, wn = wave & 1;
  const int row16 = lane & 15, kgrp = lane >> 4;

  if (z < 2) {
    unsigned short* C = z ? Kb : Qb;
#pragma unroll
    for (int mi = 0; mi < 4; mi++)
#pragma unroll
      for (int ni = 0; ni < 4; ni++)
#pragma unroll
        for (int r = 0; r < 4; r++) {
          int row = m0 + wm * 64 + mi * 16 + kgrp * 4 + r;
          int col = n0 + wn * 64 + ni * 16 + row16;
          C[(size_t)row * 1024 + col] = f2bu(acc[mi][ni][r]);
        }
  } else {
    // transpose tile via LDS: T[c_loc][m_loc], 256B rows, 16B slots XOR-swizzled by (c_loc&15)
#pragma unroll
    for (int mi = 0; mi < 4; mi++)
#pragma unroll
      for (int ni = 0; ni < 4; ni++) {
        const int m_loc = wm * 64 + mi * 16 + kgrp * 4;
        const int c_loc = wn * 64 + ni * 16 + row16;
        uint2 pk;
        pk.x = cvtpk(acc[mi][ni][0], acc[mi][ni][1]);
        pk.y = cvtpk(acc[mi][ni][2], acc[mi][ni][3]);
        const int slot = (m_loc >> 3) ^ (c_loc & 15);
        *(uint2*)((char*)lds + c_loc * 256 + slot * 16 + ((m_loc >> 2) & 1) * 8) = pk;
      }
    __syncthreads();
    // coalesced Vt stores: 8 iters x (16 lanes x 16B = 256B per dcol row)
    const int bb = m0 >> 11, mb0 = m0 & 2047;
    const int sl = tid & 15;
#pragma unroll
    for (int it = 0; it < 8; it++) {
      const int cr = it * 16 + (tid >> 4);
      const int ps = sl ^ (cr & 15);
      uint4 vv = *(const uint4*)((const char*)lds + cr * 256 + ps * 16);
      *(uint4*)&Vt[(((size_t)(bb * 1024 + n0 + cr)) << 11) + mb0 + sl * 8] = vv;
    }
  }
}

// output projection: out = attn(bf16) * Wo(bf16)^T, f32 out. 1D grid 256, XCD-aware.
__global__ __launch_bounds__(256) void gemm_wo(const unsigned short* __restrict__ A,
                                               const unsigned short* __restrict__ Bw,
                                               float* __restrict__ C) {
  __shared__ unsigned short As[128][64];
  __shared__ unsigned short Bs[128][64];
  const int xcd = blockIdx.x & 7, u = blockIdx.x >> 3;   // u 0..31
  const int g = xcd * 4 + (u >> 3);                      // m-strip 0..31
  const int m0 = g * 128, n0 = (u & 7) * 128;

  f32x4 acc[4][4] = {};
  gemm_core(A, Bw, m0, n0, acc, As, Bs);

  const int lane = threadIdx.x & 63, wave = threadIdx.x >> 6;
  const int wm = wave >> 1, wn = wave & 1;
  const int row16 = lane & 15, kgrp = lane >> 4;
#pragma unroll
  for (int mi = 0; mi < 4; mi++)
#pragma unroll
    for (int ni = 0; ni < 4; ni++)
#pragma unroll
      for (int r = 0; r < 4; r++) {
        int row = m0 + wm * 64 + mi * 16 + kgrp * 4 + r;
        int col = n0 + wn * 64 + ni * 16 + row16;
        C[(size_t)row * 1024 + col] = acc[mi][ni][r];
      }
}

// ---------------------------------------------------------------- V column sums from Vt (deterministic)
__global__ __launch_bounds__(256) void reduce_vt(const unsigned short* __restrict__ Vt,
                                                 const int* __restrict__ fu,
                                                 float* __restrict__ vsum) {
  const int b = blockIdx.x >> 10;
  if (fu[b] == 0) return;
  __shared__ float red[256];
  const unsigned short* p = Vt + ((size_t)blockIdx.x << 11) + threadIdx.x * 8;
  uint4 u = *(const uint4*)p;
  float s = b2f((unsigned short)(u.x & 0xffff));
  s += b2f((unsigned short)(u.x >> 16));
  s += b2f((unsigned short)(u.y & 0xffff));
  s += b2f((unsigned short)(u.y >> 16));
  s += b2f((unsigned short)(u.z & 0xffff));
  s += b2f((unsigned short)(u.z >> 16));
  s += b2f((unsigned short)(u.w & 0xffff));
  s += b2f((unsigned short)(u.w >> 16));
  red[threadIdx.x] = s;
  __syncthreads();
  for (int st = 128; st > 0; st >>= 1) {
    if (threadIdx.x < st) red[threadIdx.x] += red[threadIdx.x + st];
    __syncthreads();
  }
  if (threadIdx.x == 0) vsum[blockIdx.x] = red[0];
}

// ---------------------------------------------------------------- flash attention v11: V from global
// v8 minus the entire V LDS path: V^T fragments read directly from (XCD-L2-resident) Vt,
// issued after QK^T and consumed after softmax (latency hidden). LDS 40 -> 24.5 KB.
__global__ __launch_bounds__(256) void flash_attn11(const unsigned short* __restrict__ Q,
                                                    const unsigned short* __restrict__ Kp,
                                                    const unsigned short* __restrict__ Vt,
                                                    const unsigned int* __restrict__ pm,
                                                    const int* __restrict__ fu,
                                                    const float* __restrict__ vsum,
                                                    unsigned short* __restrict__ O) {
  const int S = 2048, DM = 1024;
  const int bid = blockIdx.x;                 // 0..1023
  const int qt = 31 - (bid >> 5);             // longest blocks dispatch first
  const int bh = bid & 31;
  const int b = bh >> 4, h = bh & 15;
  const int tid = threadIdx.x, lane = tid & 63, wave = tid >> 6;
  const int row16 = lane & 15, kgrp = lane >> 4;

  __shared__ unsigned short Ks[2][64][64];   // 16 KB, XOR-swizzled 16B slots
  __shared__ unsigned short Ps[4][16][64];   // 8 KB per-wave P [q][k], swizzled slots

  const size_t base = ((size_t)b * S) * DM + h * 64;
  const size_t vtb = ((size_t)(b * 1024 + h * 64)) * S;
  const unsigned int* pmb = pm + b * 1024;

  const int srow = lane >> 3;
  const int sslot = (lane & 7) ^ srow;
  const int sw = row16 & 7;

  const int q0 = qt * 64 + wave * 16;
  const int qg = q0 + row16;                 // this lane's q row (lane-local)
  const int nt = qt + 1;

  s16x8 qf0 = *(const s16x8*)&Q[base + (size_t)qg * DM + kgrp * 8];
  s16x8 qf1 = *(const s16x8*)&Q[base + (size_t)qg * DM + 32 + kgrp * 8];

  const short ONE = 0x3F80;
  const s16x8 ones8 = {ONE, ONE, ONE, ONE, ONE, ONE, ONE, ONE};

  f32x4 oacc[4] = {};
  f32x4 lacc = {};                           // running sum_k P[qg][k] (4 equal copies)
  float m_run = -1e30f;

  auto stage = [&](int t, int bf) {
    const int kb = t * 64;
#pragma unroll
    for (int c2 = 0; c2 < 2; c2++) {
      const int r = wave * 16 + c2 * 8 + srow;
      GLD16(Kp + base + (size_t)(kb + r) * DM + sslot * 8,
            (char*)&Ks[bf][0][0] + (wave * 2 + c2) * 1024);
    }
  };

  stage(0, 0);
  asm volatile("s_waitcnt vmcnt(0)" ::: "memory");
  __syncthreads();

  int cur = 0;
  for (int t = 0; t < nt; ++t) {
    if (t + 1 < nt) stage(t + 1, cur ^ 1);
    const int kb = t * 64;

    // AND-masks for this lane's 16 keys (L1-hot 8B loads, issued early)
    uint2 pmv[4];
#pragma unroll
    for (int nf = 0; nf < 4; nf++)
      pmv[nf] = *(const uint2*)&pmb[(kb + nf * 16 + kgrp * 4) >> 1];

    // S^T = K * Q^T, already in log2 domain (Q pre-scaled by 0.125*log2e)
    f32x4 sc[4];
    __builtin_amdgcn_s_setprio(1);
#pragma unroll
    for (int nf = 0; nf < 4; nf++) {
      const int rr = nf * 16 + row16;
      s16x8 k0 = *(const s16x8*)&Ks[cur][rr][(kgrp ^ sw) * 8];
      s16x8 k1 = *(const s16x8*)&Ks[cur][rr][((4 + kgrp) ^ sw) * 8];
      f32x4 a = {};
      a = MFMA16(k0, qf0, a);
      a = MFMA16(k1, qf1, a);
      sc[nf] = a;
    }
    __builtin_amdgcn_s_setprio(0);

    // V^T fragments straight from global (L2-resident); latency hides under softmax
    s16x8 vf0[4], vf1[4];
#pragma unroll
    for (int nf2 = 0; nf2 < 4; nf2++) {
      const unsigned short* vp = &Vt[vtb + (size_t)(nf2 * 16 + row16) * S + kb];
      vf0[nf2] = *(const s16x8*)(vp + kgrp * 8);
      vf1[nf2] = *(const s16x8*)(vp + 32 + kgrp * 8);
    }

    // causal: only the diagonal tile needs it (p underflows to exact 0)
    if (t == nt - 1) {
#pragma unroll
      for (int nf = 0; nf < 4; nf++) {
        const int kbase = kb + nf * 16 + kgrp * 4;
#pragma unroll
        for (int r = 0; r < 4; r++)
          if (kbase + r > qg) sc[nf][r] = -30000.0f;
      }
    }

    // max over this lane's 16 raw scores (max3-shaped tree), then 2 shfl inside defer gate
    float a0 = fmaxf(fmaxf(sc[0][0], sc[0][1]), sc[0][2]);
    float a1 = fmaxf(fmaxf(sc[0][3], sc[1][0]), sc[1][1]);
    float a2 = fmaxf(fmaxf(sc[1][2], sc[1][3]), sc[2][0]);
    float a3 = fmaxf(fmaxf(sc[2][1], sc[2][2]), sc[2][3]);
    float a4 = fmaxf(fmaxf(sc[3][0], sc[3][1]), sc[3][2]);
    float b0 = fmaxf(fmaxf(a0, a1), a2);
    float b1 = fmaxf(fmaxf(a3, a4), sc[3][3]);
    float tmax = fmaxf(b0, b1);

    if (__any(tmax > m_run)) {
      float wmax = fmaxf(tmax, __shfl_xor(tmax, 16));
      wmax = fmaxf(wmax, __shfl_xor(wmax, 32));
      float alpha = __builtin_exp2f(m_run - wmax);
      m_run = wmax;
      lacc[0] *= alpha; lacc[1] *= alpha; lacc[2] *= alpha; lacc[3] *= alpha;
#pragma unroll
      for (int nf2 = 0; nf2 < 4; nf2++)
#pragma unroll
        for (int r = 0; r < 4; r++) oacc[nf2][r] *= alpha;
    }

#pragma unroll
    for (int nf = 0; nf < 4; nf++)
#pragma unroll
      for (int r = 0; r < 4; r++)
        sc[nf][r] = __builtin_exp2f(sc[nf][r] - m_run);

    // P pack via cvt_pk + AND-mask -> XOR-swizzled Ps
#pragma unroll
    for (int nf = 0; nf < 4; nf++) {
      uint2 pk;
      pk.x = cvtpk(sc[nf][0], sc[nf][1]) & pmv[nf].x;
      pk.y = cvtpk(sc[nf][2], sc[nf][3]) & pmv[nf].y;
      const int slot = (nf * 2 + (kgrp >> 1)) ^ sw;
      *(uint2*)((char*)&Ps[wave][row16][0] + slot * 16 + (kgrp & 1) * 8) = pk;
    }
    s16x8 pf0 = *(const s16x8*)((char*)&Ps[wave][row16][0] + (kgrp ^ sw) * 16);
    s16x8 pf1 = *(const s16x8*)((char*)&Ps[wave][row16][0] + ((4 + kgrp) ^ sw) * 16);

    // O^T += V^T * P^T; l += 1^T * P^T (row-sum on the matrix pipe; P already masked)
    __builtin_amdgcn_s_setprio(1);
    lacc = MFMA16(ones8, pf0, lacc);
    lacc = MFMA16(ones8, pf1, lacc);
#pragma unroll
    for (int nf2 = 0; nf2 < 4; nf2++) {
      oacc[nf2] = MFMA16(vf0[nf2], pf0, oacc[nf2]);
      oacc[nf2] = MFMA16(vf1[nf2], pf1, oacc[nf2]);
    }
    __builtin_amdgcn_s_setprio(0);

    asm volatile("s_waitcnt vmcnt(0)" ::: "memory");
    __syncthreads();
    cur ^= 1;
  }

  // epilogue: lane owns q=qg, d = nf2*16 + kgrp*4 + r -> packed bf16 stores
  const int fub = fu[b];
  const float* vs = vsum + b * DM + h * 64;
  const float rl = 1.0f / lacc[0];
#pragma unroll
  for (int nf2 = 0; nf2 < 4; nf2++) {
    const int d0 = nf2 * 16 + kgrp * 4;
    float v0 = oacc[nf2][0] * rl, v1 = oacc[nf2][1] * rl;
    float v2 = oacc[nf2][2] * rl, v3 = oacc[nf2][3] * rl;
    if (qg < fub) {
      float4 vv = *(const float4*)&vs[d0];
      v0 = vv.x * (1.0f / 2048.0f);
      v1 = vv.y * (1.0f / 2048.0f);
      v2 = vv.z * (1.0f / 2048.0f);
      v3 = vv.w * (1.0f / 2048.0f);
    }
    uint2 pk;
    pk.x = cvtpk(v0, v1);
    pk.y = cvtpk(v2, v3);
    *(uint2*)&O[base + (size_t)qg * DM + d0] = pk;
  }
}

// ---------------------------------------------------------------- launch
extern "C" void kernel_launch(void* const* d_in, const int* in_sizes, int n_in,
                              void* d_out, int out_size, void* d_ws, size_t ws_size,
                              hipStream_t stream) {
  const float* q    = (const float*)d_in[0];
  const float* k    = (const float*)d_in[1];
  const float* v    = (const float*)d_in[2];
  const int*   mask = (const int*)d_in[3];
  const float* Wq   = (const float*)d_in[4];
  const float* Wk   = (const float*)d_in[5];
  const float* Wv   = (const float*)d_in[6];
  const float* Wo   = (const float*)d_in[7];
  float* out = (float*)d_out;
  char* ws = (char*)d_ws;

  unsigned short* Wqb  = (unsigned short*)(ws + (size_t)0);
  unsigned short* Wkb  = (unsigned short*)(ws + ((size_t)2 << 20));
  unsigned short* Wvb  = (unsigned short*)(ws + ((size_t)4 << 20));
  unsigned short* Wob  = (unsigned short*)(ws + ((size_t)6 << 20));
  unsigned short* vc   = (unsigned short*)(ws + ((size_t)8 << 20));   // dead after qkv_gemm
  unsigned short* attn = (unsigned short*)(ws + ((size_t)8 << 20));   // aliases vc
  unsigned short* Qb   = (unsigned short*)(ws + ((size_t)16 << 20));
  unsigned short* Kb   = (unsigned short*)(ws + ((size_t)24 << 20));
  unsigned short* Vt   = (unsigned short*)(ws + ((size_t)32 << 20));
  float* vsum          = (float*)(ws + ((size_t)40 << 20));
  int*   fub           = (int*)(ws + ((size_t)40 << 20) + (64 << 10));
  unsigned int* pm32   = (unsigned int*)(ws + ((size_t)40 << 20) + (68 << 10));
  unsigned short* qc   = (unsigned short*)d_out;                      // d_out as cast scratch
  unsigned short* kc   = (unsigned short*)d_out + 4194304;

  cast_all<<<8194, 256, 0, stream>>>(q, k, v, Wq, Wk, Wv, Wo, mask,
                                     qc, kc, vc, Wqb, Wkb, Wvb, Wob, fub, pm32);

  qkv_gemm<<<768, 256, 0, stream>>>(qc, kc, vc, Wqb, Wkb, Wvb, Qb, Kb, Vt);

  reduce_vt<<<2048, 256, 0, stream>>>(Vt, fub, vsum);

  flash_attn11<<<1024, 256, 0, stream>>>(Qb, Kb, Vt, pm32, fub, vsum, attn);

  gemm_wo<<<256, 256, 0, stream>>>(attn, Wob, out);
}

// Round 19
// 135.731 us; speedup vs baseline: 1.2534x; 1.2534x over previous
//
#include <hip/hip_runtime.h>
#include <hip/hip_bf16.h>
#include <math.h>

typedef __attribute__((ext_vector_type(8))) short s16x8;
typedef __attribute__((ext_vector_type(4))) float f32x4;

#define MFMA16(a,b,c) __builtin_amdgcn_mfma_f32_16x16x32_bf16((a),(b),(c),0,0,0)

#define GLD16(gp, lp) __builtin_amdgcn_global_load_lds( \
  (const __attribute__((address_space(1))) unsigned int*)(gp), \
  (__attribute__((address_space(3))) unsigned int*)(lp), 16, 0, 0)

static __device__ __forceinline__ unsigned short f2bu(float f) {
  __hip_bfloat16 h = __float2bfloat16(f);
  unsigned short u; __builtin_memcpy(&u, &h, 2); return u;
}
static __device__ __forceinline__ float b2f(unsigned short u) {
  unsigned int x = ((unsigned int)u) << 16; float f; __builtin_memcpy(&f, &x, 4); return f;
}
// 2 f32 -> packed bf16 pair in one HW op (lo = s0, hi = s1)
static __device__ __forceinline__ unsigned int cvtpk(float lo, float hi) {
  unsigned int r;
  asm("v_cvt_pk_bf16_f32 %0, %1, %2" : "=v"(r) : "v"(lo), "v"(hi));
  return r;
}

// ---------------------------------------------------------------- cast (exact 1D grid, 32B/thread) + fu/pairmask
__global__ __launch_bounds__(256) void cast_all(const float* __restrict__ q, const float* __restrict__ k,
                                                const float* __restrict__ v,
                                                const float* __restrict__ Wq, const float* __restrict__ Wk,
                                                const float* __restrict__ Wv, const float* __restrict__ Wo,
                                                const int* __restrict__ mask,
                                                unsigned short* __restrict__ qc, unsigned short* __restrict__ kc,
                                                unsigned short* __restrict__ vc,
                                                unsigned short* __restrict__ wq, unsigned short* __restrict__ wk,
                                                unsigned short* __restrict__ wv, unsigned short* __restrict__ wo,
                                                int* __restrict__ fu, unsigned int* __restrict__ pm) {
  const float SCALE2 = 0.125f * 1.4426950408889634f;   // folded into Wq -> QK^T lands in log2 domain
  const int bid = blockIdx.x;
  if (bid < 6144) {
    const int y = bid >> 11;                 // 0,1,2
    const float* in = (y == 0) ? q : (y == 1) ? k : v;
    unsigned short* out = (y == 0) ? qc : (y == 1) ? kc : vc;
    const size_t i = (size_t)(bid & 2047) * 256 + threadIdx.x;  // 8 floats each
    const float4* p = (const float4*)(in + i * 8);
    float4 v0 = p[0], v1 = p[1];
    uint4 pk;
    pk.x = cvtpk(v0.x, v0.y); pk.y = cvtpk(v0.z, v0.w);
    pk.z = cvtpk(v1.x, v1.y); pk.w = cvtpk(v1.z, v1.w);
    *(uint4*)(out + i * 8) = pk;
  } else if (bid < 8192) {
    const int r = bid - 6144;
    const int y = r >> 9;                    // 0..3
    const float scl = (y == 0) ? SCALE2 : 1.0f;
    const float* in = (y == 0) ? Wq : (y == 1) ? Wk : (y == 2) ? Wv : Wo;
    unsigned short* out = (y == 0) ? wq : (y == 1) ? wk : (y == 2) ? wv : wo;
    const size_t i = (size_t)(r & 511) * 256 + threadIdx.x;
    const float4* p = (const float4*)(in + i * 8);
    float4 v0 = p[0], v1 = p[1];
    uint4 pk;
    pk.x = cvtpk(v0.x * scl, v0.y * scl); pk.y = cvtpk(v0.z * scl, v0.w * scl);
    pk.z = cvtpk(v1.x * scl, v1.y * scl); pk.w = cvtpk(v1.z * scl, v1.w * scl);
    *(uint4*)(out + i * 8) = pk;
  } else {
    const int S = 2048;
    const int b = bid - 8192;                // 0,1
    __shared__ int red[256];
    int best = S;
    for (int kk = threadIdx.x; kk < 1024; kk += 256) {
      int m0 = mask[b * S + 2 * kk], m1 = mask[b * S + 2 * kk + 1];
      pm[b * 1024 + kk] = (m0 ? 0xFFFFu : 0u) | (m1 ? 0xFFFF0000u : 0u);
      if (m1) best = min(best, 2 * kk + 1);
      if (m0) best = min(best, 2 * kk);
    }
    red[threadIdx.x] = best;
    __syncthreads();
    for (int s = 128; s > 0; s >>= 1) {
      if (threadIdx.x < s) red[threadIdx.x] = min(red[threadIdx.x], red[threadIdx.x + s]);
      __syncthreads();
    }
    if (threadIdx.x == 0) fu[b] = red[0];
  }
}

// ---------------------------------------------------------------- shared GEMM core: C = A(bf16) * Bw(bf16)^T
static __device__ __forceinline__ void gemm_core(const unsigned short* __restrict__ Aw,
                                                 const unsigned short* __restrict__ Bw,
                                                 int m0, int n0,
                                                 f32x4 (&acc)[4][4],
                                                 unsigned short (*As)[64], unsigned short (*Bs)[64]) {
  const int K = 1024;
  const int tid = threadIdx.x;
  const int lane = tid & 63, wave = tid >> 6;
  const int wm = wave >> 1, wn = wave & 1;
  const int row16 = lane & 15, kgrp = lane >> 4;
  const int srow = lane >> 3, sslot = (lane & 7) ^ srow;
  const int sw = row16 & 7;

  for (int k0 = 0; k0 < K; k0 += 64) {
#pragma unroll
    for (int i = 0; i < 4; i++) {
      int rr = (wave * 4 + i) * 8 + srow;
      GLD16(Aw + (size_t)(m0 + rr) * K + k0 + sslot * 8, (char*)As + (wave * 4 + i) * 1024);
      GLD16(Bw + (size_t)(n0 + rr) * K + k0 + sslot * 8, (char*)Bs + (wave * 4 + i) * 1024);
    }
    __syncthreads();

#pragma unroll
    for (int kk = 0; kk < 2; kk++) {
      s16x8 af[4], bfr[4];
#pragma unroll
      for (int mi = 0; mi < 4; mi++) {
        int rr = wm * 64 + mi * 16 + row16;
        af[mi] = *(const s16x8*)((char*)&As[rr][0] + ((kk * 4 + kgrp) ^ sw) * 16);
      }
#pragma unroll
      for (int ni = 0; ni < 4; ni++) {
        int rr = wn * 64 + ni * 16 + row16;
        bfr[ni] = *(const s16x8*)((char*)&Bs[rr][0] + ((kk * 4 + kgrp) ^ sw) * 16);
      }
#pragma unroll
      for (int mi = 0; mi < 4; mi++)
#pragma unroll
        for (int ni = 0; ni < 4; ni++)
          acc[mi][ni] = MFMA16(af[mi], bfr[ni], acc[mi][ni]);
    }
    __syncthreads();
  }
}

// fused Q/K/V projection, 1D grid 768, XCD-aware. z=2 writes Vt transposed
// (via LDS transpose -> coalesced 16B stores); z<2 scalar stores (L2-absorbed, measured best).
__global__ __launch_bounds__(256) void qkv_gemm(const unsigned short* __restrict__ qc,
                                                const unsigned short* __restrict__ kc,
                                                const unsigned short* __restrict__ vc,
                                                const unsigned short* __restrict__ Wqb,
                                                const unsigned short* __restrict__ Wkb,
                                                const unsigned short* __restrict__ Wvb,
                                                unsigned short* __restrict__ Qb,
                                                unsigned short* __restrict__ Kb,
                                                unsigned short* __restrict__ Vt) {
  __shared__ unsigned short lds[16384];                  // 32 KB: As|Bs during GEMM, T after
  unsigned short (*As)[64] = (unsigned short (*)[64])lds;
  unsigned short (*Bs)[64] = (unsigned short (*)[64])(lds + 8192);
  const int xcd = blockIdx.x & 7, u = blockIdx.x >> 3;   // u 0..95
  const int g = xcd * 12 + (u >> 3);                     // unit 0..95
  const int z = g >> 5, mstrip = g & 31;
  const int m0 = mstrip * 128, n0 = (u & 7) * 128;

  const unsigned short* A = (z == 0) ? qc : (z == 1) ? kc : vc;
  const unsigned short* Bw = (z == 0) ? Wqb : (z == 1) ? Wkb : Wvb;

  f32x4 acc[4][4] = {};
  gemm_core(A, Bw, m0, n0, acc, As, Bs);

  const int tid = threadIdx.x;
  const int lane = tid & 63, wave = tid >> 6;
  const int wm = wave >> 1, wn = wave & 1;
  const int row16 = lane & 15, kgrp = lane >> 4;

  if (z < 2) {
    unsigned short* C = z ? Kb : Qb;
#pragma unroll
    for (int mi = 0; mi < 4; mi++)
#pragma unroll
      for (int ni = 0; ni < 4; ni++)
#pragma unroll
        for (int r = 0; r < 4; r++) {
          int row = m0 + wm * 64 + mi * 16 + kgrp * 4 + r;
          int col = n0 + wn * 64 + ni * 16 + row16;
          C[(size_t)row * 1024 + col] = f2bu(acc[mi][ni][r]);
        }
  } else {
    // transpose tile via LDS: T[c_loc][m_loc], 256B rows, 16B slots XOR-swizzled by (c_loc&15)
#pragma unroll
    for (int mi = 0; mi < 4; mi++)
#pragma unroll
      for (int ni = 0; ni < 4; ni++) {
        const int m_loc = wm * 64 + mi * 16 + kgrp * 4;
        const int c_loc = wn * 64 + ni * 16 + row16;
        uint2 pk;
        pk.x = cvtpk(acc[mi][ni][0], acc[mi][ni][1]);
        pk.y = cvtpk(acc[mi][ni][2], acc[mi][ni][3]);
        const int slot = (m_loc >> 3) ^ (c_loc & 15);
        *(uint2*)((char*)lds + c_loc * 256 + slot * 16 + ((m_loc >> 2) & 1) * 8) = pk;
      }
    __syncthreads();
    // coalesced Vt stores: 8 iters x (16 lanes x 16B = 256B per dcol row)
    const int bb = m0 >> 11, mb0 = m0 & 2047;
    const int sl = tid & 15;
#pragma unroll
    for (int it = 0; it < 8; it++) {
      const int cr = it * 16 + (tid >> 4);
      const int ps = sl ^ (cr & 15);
      uint4 vv = *(const uint4*)((const char*)lds + cr * 256 + ps * 16);
      *(uint4*)&Vt[(((size_t)(bb * 1024 + n0 + cr)) << 11) + mb0 + sl * 8] = vv;
    }
  }
}

// output projection: out = attn(bf16) * Wo(bf16)^T, f32 out. 1D grid 256, XCD-aware.
__global__ __launch_bounds__(256) void gemm_wo(const unsigned short* __restrict__ A,
                                               const unsigned short* __restrict__ Bw,
                                               float* __restrict__ C) {
  __shared__ unsigned short As[128][64];
  __shared__ unsigned short Bs[128][64];
  const int xcd = blockIdx.x & 7, u = blockIdx.x >> 3;   // u 0..31
  const int g = xcd * 4 + (u >> 3);                      // m-strip 0..31
  const int m0 = g * 128, n0 = (u & 7) * 128;

  f32x4 acc[4][4] = {};
  gemm_core(A, Bw, m0, n0, acc, As, Bs);

  const int lane = threadIdx.x & 63, wave = threadIdx.x >> 6;
  const int wm = wave >> 1, wn = wave & 1;
  const int row16 = lane & 15, kgrp = lane >> 4;
#pragma unroll
  for (int mi = 0; mi < 4; mi++)
#pragma unroll
    for (int ni = 0; ni < 4; ni++)
#pragma unroll
      for (int r = 0; r < 4; r++) {
        int row = m0 + wm * 64 + mi * 16 + kgrp * 4 + r;
        int col = n0 + wn * 64 + ni * 16 + row16;
        C[(size_t)row * 1024 + col] = acc[mi][ni][r];
      }
}

// ---------------------------------------------------------------- V column sums from Vt (deterministic)
// Early-exit: vsum[b] is read by flash only for rows qg < fu[b]; if fu[b]==0 nothing reads it.
__global__ __launch_bounds__(256) void reduce_vt(const unsigned short* __restrict__ Vt,
                                                 const int* __restrict__ fu,
                                                 float* __restrict__ vsum) {
  const int b = blockIdx.x >> 10;
  if (fu[b] == 0) return;
  __shared__ float red[256];
  const unsigned short* p = Vt + ((size_t)blockIdx.x << 11) + threadIdx.x * 8;
  uint4 u = *(const uint4*)p;
  float s = b2f((unsigned short)(u.x & 0xffff));
  s += b2f((unsigned short)(u.x >> 16));
  s += b2f((unsigned short)(u.y & 0xffff));
  s += b2f((unsigned short)(u.y >> 16));
  s += b2f((unsigned short)(u.z & 0xffff));
  s += b2f((unsigned short)(u.z >> 16));
  s += b2f((unsigned short)(u.w & 0xffff));
  s += b2f((unsigned short)(u.w >> 16));
  red[threadIdx.x] = s;
  __syncthreads();
  for (int st = 128; st > 0; st >>= 1) {
    if (threadIdx.x < st) red[threadIdx.x] += red[threadIdx.x + st];
    __syncthreads();
  }
  if (threadIdx.x == 0) vsum[blockIdx.x] = red[0];
}

// ---------------------------------------------------------------- flash attention v8 (best measured: 56.4us)
__global__ __launch_bounds__(256) void flash_attn8(const unsigned short* __restrict__ Q,
                                                   const unsigned short* __restrict__ Kp,
                                                   const unsigned short* __restrict__ Vt,
                                                   const unsigned int* __restrict__ pm,
                                                   const int* __restrict__ fu,
                                                   const float* __restrict__ vsum,
                                                   unsigned short* __restrict__ O) {
  const int S = 2048, DM = 1024;
  const int bid = blockIdx.x;                 // 0..1023
  const int qt = 31 - (bid >> 5);             // longest blocks dispatch first
  const int bh = bid & 31;
  const int b = bh >> 4, h = bh & 15;
  const int tid = threadIdx.x, lane = tid & 63, wave = tid >> 6;
  const int row16 = lane & 15, kgrp = lane >> 4;

  __shared__ unsigned short Ks[2][64][64];   // 16 KB, XOR-swizzled 16B slots
  __shared__ unsigned short Vs[2][64][64];   // 16 KB (V^T tile), swizzled
  __shared__ unsigned short Ps[4][16][64];   // 8 KB per-wave P [q][k], swizzled slots

  const size_t base = ((size_t)b * S) * DM + h * 64;
  const size_t vtb = ((size_t)(b * 1024 + h * 64)) * S;
  const unsigned int* pmb = pm + b * 1024;

  const int srow = lane >> 3;
  const int sslot = (lane & 7) ^ srow;
  const int sw = row16 & 7;

  const int q0 = qt * 64 + wave * 16;
  const int qg = q0 + row16;                 // this lane's q row (lane-local)
  const int nt = qt + 1;

  s16x8 qf0 = *(const s16x8*)&Q[base + (size_t)qg * DM + kgrp * 8];
  s16x8 qf1 = *(const s16x8*)&Q[base + (size_t)qg * DM + 32 + kgrp * 8];

  const short ONE = 0x3F80;
  const s16x8 ones8 = {ONE, ONE, ONE, ONE, ONE, ONE, ONE, ONE};

  f32x4 oacc[4] = {};
  f32x4 lacc = {};                           // running sum_k P[qg][k] (4 equal copies)
  float m_run = -1e30f;

  auto stage = [&](int t, int bf) {
    const int kb = t * 64;
#pragma unroll
    for (int c2 = 0; c2 < 2; c2++) {
      const int r = wave * 16 + c2 * 8 + srow;
      GLD16(Kp + base + (size_t)(kb + r) * DM + sslot * 8,
            (char*)&Ks[bf][0][0] + (wave * 2 + c2) * 1024);
      GLD16(Vt + vtb + (size_t)r * S + kb + sslot * 8,
            (char*)&Vs[bf][0][0] + (wave * 2 + c2) * 1024);
    }
  };

  stage(0, 0);
  asm volatile("s_waitcnt vmcnt(0)" ::: "memory");
  __syncthreads();

  int cur = 0;
  for (int t = 0; t < nt; ++t) {
    if (t + 1 < nt) stage(t + 1, cur ^ 1);
    const int kb = t * 64;

    // AND-masks for this lane's 16 keys (L1-hot 8B loads, issued early)
    uint2 pmv[4];
#pragma unroll
    for (int nf = 0; nf < 4; nf++)
      pmv[nf] = *(const uint2*)&pmb[(kb + nf * 16 + kgrp * 4) >> 1];

    // S^T = K * Q^T, already in log2 domain (Q pre-scaled by 0.125*log2e)
    f32x4 sc[4];
    __builtin_amdgcn_s_setprio(1);
#pragma unroll
    for (int nf = 0; nf < 4; nf++) {
      const int rr = nf * 16 + row16;
      s16x8 k0 = *(const s16x8*)&Ks[cur][rr][(kgrp ^ sw) * 8];
      s16x8 k1 = *(const s16x8*)&Ks[cur][rr][((4 + kgrp) ^ sw) * 8];
      f32x4 a = {};
      a = MFMA16(k0, qf0, a);
      a = MFMA16(k1, qf1, a);
      sc[nf] = a;
    }
    __builtin_amdgcn_s_setprio(0);

    // causal: only the diagonal tile needs it (p underflows to exact 0)
    if (t == nt - 1) {
#pragma unroll
      for (int nf = 0; nf < 4; nf++) {
        const int kbase = kb + nf * 16 + kgrp * 4;
#pragma unroll
        for (int r = 0; r < 4; r++)
          if (kbase + r > qg) sc[nf][r] = -30000.0f;
      }
    }

    // max over this lane's 16 raw scores (max3-shaped tree), then 2 shfl inside defer gate
    float a0 = fmaxf(fmaxf(sc[0][0], sc[0][1]), sc[0][2]);
    float a1 = fmaxf(fmaxf(sc[0][3], sc[1][0]), sc[1][1]);
    float a2 = fmaxf(fmaxf(sc[1][2], sc[1][3]), sc[2][0]);
    float a3 = fmaxf(fmaxf(sc[2][1], sc[2][2]), sc[2][3]);
    float a4 = fmaxf(fmaxf(sc[3][0], sc[3][1]), sc[3][2]);
    float b0 = fmaxf(fmaxf(a0, a1), a2);
    float b1 = fmaxf(fmaxf(a3, a4), sc[3][3]);
    float tmax = fmaxf(b0, b1);

    if (__any(tmax > m_run)) {
      float wmax = fmaxf(tmax, __shfl_xor(tmax, 16));
      wmax = fmaxf(wmax, __shfl_xor(wmax, 32));
      float alpha = __builtin_exp2f(m_run - wmax);
      m_run = wmax;
      lacc[0] *= alpha; lacc[1] *= alpha; lacc[2] *= alpha; lacc[3] *= alpha;
#pragma unroll
      for (int nf2 = 0; nf2 < 4; nf2++)
#pragma unroll
        for (int r = 0; r < 4; r++) oacc[nf2][r] *= alpha;
    }

#pragma unroll
    for (int nf = 0; nf < 4; nf++)
#pragma unroll
      for (int r = 0; r < 4; r++)
        sc[nf][r] = __builtin_exp2f(sc[nf][r] - m_run);

    // P pack via cvt_pk + AND-mask -> XOR-swizzled Ps
#pragma unroll
    for (int nf = 0; nf < 4; nf++) {
      uint2 pk;
      pk.x = cvtpk(sc[nf][0], sc[nf][1]) & pmv[nf].x;
      pk.y = cvtpk(sc[nf][2], sc[nf][3]) & pmv[nf].y;
      const int slot = (nf * 2 + (kgrp >> 1)) ^ sw;
      *(uint2*)((char*)&Ps[wave][row16][0] + slot * 16 + (kgrp & 1) * 8) = pk;
    }
    s16x8 pf0 = *(const s16x8*)((char*)&Ps[wave][row16][0] + (kgrp ^ sw) * 16);
    s16x8 pf1 = *(const s16x8*)((char*)&Ps[wave][row16][0] + ((4 + kgrp) ^ sw) * 16);

    // O^T += V^T * P^T; l += 1^T * P^T (row-sum on the matrix pipe; P already masked)
    __builtin_amdgcn_s_setprio(1);
    lacc = MFMA16(ones8, pf0, lacc);
    lacc = MFMA16(ones8, pf1, lacc);
#pragma unroll
    for (int nf2 = 0; nf2 < 4; nf2++) {
      const int rr = nf2 * 16 + row16;
      s16x8 v0 = *(const s16x8*)&Vs[cur][rr][(kgrp ^ sw) * 8];
      s16x8 v1 = *(const s16x8*)&Vs[cur][rr][((4 + kgrp) ^ sw) * 8];
      oacc[nf2] = MFMA16(v0, pf0, oacc[nf2]);
      oacc[nf2] = MFMA16(v1, pf1, oacc[nf2]);
    }
    __builtin_amdgcn_s_setprio(0);

    asm volatile("s_waitcnt vmcnt(0)" ::: "memory");
    __syncthreads();
    cur ^= 1;
  }

  // epilogue: lane owns q=qg, d = nf2*16 + kgrp*4 + r -> packed bf16 stores
  const int fub = fu[b];
  const float* vs = vsum + b * DM + h * 64;
  const float rl = 1.0f / lacc[0];
#pragma unroll
  for (int nf2 = 0; nf2 < 4; nf2++) {
    const int d0 = nf2 * 16 + kgrp * 4;
    float v0 = oacc[nf2][0] * rl, v1 = oacc[nf2][1] * rl;
    float v2 = oacc[nf2][2] * rl, v3 = oacc[nf2][3] * rl;
    if (qg < fub) {
      float4 vv = *(const float4*)&vs[d0];
      v0 = vv.x * (1.0f / 2048.0f);
      v1 = vv.y * (1.0f / 2048.0f);
      v2 = vv.z * (1.0f / 2048.0f);
      v3 = vv.w * (1.0f / 2048.0f);
    }
    uint2 pk;
    pk.x = cvtpk(v0, v1);
    pk.y = cvtpk(v2, v3);
    *(uint2*)&O[base + (size_t)qg * DM + d0] = pk;
  }
}

// ---------------------------------------------------------------- launch
extern "C" void kernel_launch(void* const* d_in, const int* in_sizes, int n_in,
                              void* d_out, int out_size, void* d_ws, size_t ws_size,
                              hipStream_t stream) {
  const float* q    = (const float*)d_in[0];
  const float* k    = (const float*)d_in[1];
  const float* v    = (const float*)d_in[2];
  const int*   mask = (const int*)d_in[3];
  const float* Wq   = (const float*)d_in[4];
  const float* Wk   = (const float*)d_in[5];
  const float* Wv   = (const float*)d_in[6];
  const float* Wo   = (const float*)d_in[7];
  float* out = (float*)d_out;
  char* ws = (char*)d_ws;

  unsigned short* Wqb  = (unsigned short*)(ws + (size_t)0);
  unsigned short* Wkb  = (unsigned short*)(ws + ((size_t)2 << 20));
  unsigned short* Wvb  = (unsigned short*)(ws + ((size_t)4 << 20));
  unsigned short* Wob  = (unsigned short*)(ws + ((size_t)6 << 20));
  unsigned short* vc   = (unsigned short*)(ws + ((size_t)8 << 20));   // dead after qkv_gemm
  unsigned short* attn = (unsigned short*)(ws + ((size_t)8 << 20));   // aliases vc
  unsigned short* Qb   = (unsigned short*)(ws + ((size_t)16 << 20));
  unsigned short* Kb   = (unsigned short*)(ws + ((size_t)24 << 20));
  unsigned short* Vt   = (unsigned short*)(ws + ((size_t)32 << 20));
  float* vsum          = (float*)(ws + ((size_t)40 << 20));
  int*   fub           = (int*)(ws + ((size_t)40 << 20) + (64 << 10));
  unsigned int* pm32   = (unsigned int*)(ws + ((size_t)40 << 20) + (68 << 10));
  unsigned short* qc   = (unsigned short*)d_out;                      // d_out as cast scratch
  unsigned short* kc   = (unsigned short*)d_out + 4194304;

  cast_all<<<8194, 256, 0, stream>>>(q, k, v, Wq, Wk, Wv, Wo, mask,
                                     qc, kc, vc, Wqb, Wkb, Wvb, Wob, fub, pm32);

  qkv_gemm<<<768, 256, 0, stream>>>(qc, kc, vc, Wqb, Wkb, Wvb, Qb, Kb, Vt);

  reduce_vt<<<2048, 256, 0, stream>>>(Vt, fub, vsum);

  flash_attn8<<<1024, 256, 0, stream>>>(Qb, Kb, Vt, pm32, fub, vsum, attn);

  gemm_wo<<<256, 256, 0, stream>>>(attn, Wob, out);
}

// Round 20
// 135.697 us; speedup vs baseline: 1.2537x; 1.0003x over previous
//
#include <hip/hip_runtime.h>
#include <hip/hip_bf16.h>
#include <math.h>

typedef __attribute__((ext_vector_type(8))) short s16x8;
typedef __attribute__((ext_vector_type(4))) float f32x4;

#define MFMA16(a,b,c) __builtin_amdgcn_mfma_f32_16x16x32_bf16((a),(b),(c),0,0,0)

#define GLD16(gp, lp) __builtin_amdgcn_global_load_lds( \
  (const __attribute__((address_space(1))) unsigned int*)(gp), \
  (__attribute__((address_space(3))) unsigned int*)(lp), 16, 0, 0)

static __device__ __forceinline__ unsigned short f2bu(float f) {
  __hip_bfloat16 h = __float2bfloat16(f);
  unsigned short u; __builtin_memcpy(&u, &h, 2); return u;
}
static __device__ __forceinline__ float b2f(unsigned short u) {
  unsigned int x = ((unsigned int)u) << 16; float f; __builtin_memcpy(&f, &x, 4); return f;
}
// 2 f32 -> packed bf16 pair in one HW op (lo = s0, hi = s1)
static __device__ __forceinline__ unsigned int cvtpk(float lo, float hi) {
  unsigned int r;
  asm("v_cvt_pk_bf16_f32 %0, %1, %2" : "=v"(r) : "v"(lo), "v"(hi));
  return r;
}

// ---------------------------------------------------------------- cast (exact 1D grid, 32B/thread) + fu/pairmask
__global__ __launch_bounds__(256) void cast_all(const float* __restrict__ q, const float* __restrict__ k,
                                                const float* __restrict__ v,
                                                const float* __restrict__ Wq, const float* __restrict__ Wk,
                                                const float* __restrict__ Wv, const float* __restrict__ Wo,
                                                const int* __restrict__ mask,
                                                unsigned short* __restrict__ qc, unsigned short* __restrict__ kc,
                                                unsigned short* __restrict__ vc,
                                                unsigned short* __restrict__ wq, unsigned short* __restrict__ wk,
                                                unsigned short* __restrict__ wv, unsigned short* __restrict__ wo,
                                                int* __restrict__ fu, unsigned int* __restrict__ pm) {
  const float SCALE2 = 0.125f * 1.4426950408889634f;   // folded into Wq -> QK^T lands in log2 domain
  const int bid = blockIdx.x;
  if (bid < 6144) {
    const int y = bid >> 11;                 // 0,1,2
    const float* in = (y == 0) ? q : (y == 1) ? k : v;
    unsigned short* out = (y == 0) ? qc : (y == 1) ? kc : vc;
    const size_t i = (size_t)(bid & 2047) * 256 + threadIdx.x;  // 8 floats each
    const float4* p = (const float4*)(in + i * 8);
    float4 v0 = p[0], v1 = p[1];
    uint4 pk;
    pk.x = cvtpk(v0.x, v0.y); pk.y = cvtpk(v0.z, v0.w);
    pk.z = cvtpk(v1.x, v1.y); pk.w = cvtpk(v1.z, v1.w);
    *(uint4*)(out + i * 8) = pk;
  } else if (bid < 8192) {
    const int r = bid - 6144;
    const int y = r >> 9;                    // 0..3
    const float scl = (y == 0) ? SCALE2 : 1.0f;
    const float* in = (y == 0) ? Wq : (y == 1) ? Wk : (y == 2) ? Wv : Wo;
    unsigned short* out = (y == 0) ? wq : (y == 1) ? wk : (y == 2) ? wv : wo;
    const size_t i = (size_t)(r & 511) * 256 + threadIdx.x;
    const float4* p = (const float4*)(in + i * 8);
    float4 v0 = p[0], v1 = p[1];
    uint4 pk;
    pk.x = cvtpk(v0.x * scl, v0.y * scl); pk.y = cvtpk(v0.z * scl, v0.w * scl);
    pk.z = cvtpk(v1.x * scl, v1.y * scl); pk.w = cvtpk(v1.z * scl, v1.w * scl);
    *(uint4*)(out + i * 8) = pk;
  } else {
    const int S = 2048;
    const int b = bid - 8192;                // 0,1
    __shared__ int red[256];
    int best = S;
    for (int kk = threadIdx.x; kk < 1024; kk += 256) {
      int m0 = mask[b * S + 2 * kk], m1 = mask[b * S + 2 * kk + 1];
      pm[b * 1024 + kk] = (m0 ? 0xFFFFu : 0u) | (m1 ? 0xFFFF0000u : 0u);
      if (m1) best = min(best, 2 * kk + 1);
      if (m0) best = min(best, 2 * kk);
    }
    red[threadIdx.x] = best;
    __syncthreads();
    for (int s = 128; s > 0; s >>= 1) {
      if (threadIdx.x < s) red[threadIdx.x] = min(red[threadIdx.x], red[threadIdx.x + s]);
      __syncthreads();
    }
    if (threadIdx.x == 0) fu[b] = red[0];
  }
}

// ---------------------------------------------------------------- shared GEMM core: C = A(bf16) * Bw(bf16)^T
static __device__ __forceinline__ void gemm_core(const unsigned short* __restrict__ Aw,
                                                 const unsigned short* __restrict__ Bw,
                                                 int m0, int n0,
                                                 f32x4 (&acc)[4][4],
                                                 unsigned short (*As)[64], unsigned short (*Bs)[64]) {
  const int K = 1024;
  const int tid = threadIdx.x;
  const int lane = tid & 63, wave = tid >> 6;
  const int wm = wave >> 1, wn = wave & 1;
  const int row16 = lane & 15, kgrp = lane >> 4;
  const int srow = lane >> 3, sslot = (lane & 7) ^ srow;
  const int sw = row16 & 7;

  for (int k0 = 0; k0 < K; k0 += 64) {
#pragma unroll
    for (int i = 0; i < 4; i++) {
      int rr = (wave * 4 + i) * 8 + srow;
      GLD16(Aw + (size_t)(m0 + rr) * K + k0 + sslot * 8, (char*)As + (wave * 4 + i) * 1024);
      GLD16(Bw + (size_t)(n0 + rr) * K + k0 + sslot * 8, (char*)Bs + (wave * 4 + i) * 1024);
    }
    __syncthreads();

#pragma unroll
    for (int kk = 0; kk < 2; kk++) {
      s16x8 af[4], bfr[4];
#pragma unroll
      for (int mi = 0; mi < 4; mi++) {
        int rr = wm * 64 + mi * 16 + row16;
        af[mi] = *(const s16x8*)((char*)&As[rr][0] + ((kk * 4 + kgrp) ^ sw) * 16);
      }
#pragma unroll
      for (int ni = 0; ni < 4; ni++) {
        int rr = wn * 64 + ni * 16 + row16;
        bfr[ni] = *(const s16x8*)((char*)&Bs[rr][0] + ((kk * 4 + kgrp) ^ sw) * 16);
      }
#pragma unroll
      for (int mi = 0; mi < 4; mi++)
#pragma unroll
        for (int ni = 0; ni < 4; ni++)
          acc[mi][ni] = MFMA16(af[mi], bfr[ni], acc[mi][ni]);
    }
    __syncthreads();
  }
}

// fused Q/K/V projection, 1D grid 768, XCD-aware. z=2 writes Vt transposed
// (via LDS transpose -> coalesced 16B stores); z<2 scalar stores (L2-absorbed, measured best).
__global__ __launch_bounds__(256) void qkv_gemm(const unsigned short* __restrict__ qc,
                                                const unsigned short* __restrict__ kc,
                                                const unsigned short* __restrict__ vc,
                                                const unsigned short* __restrict__ Wqb,
                                                const unsigned short* __restrict__ Wkb,
                                                const unsigned short* __restrict__ Wvb,
                                                unsigned short* __restrict__ Qb,
                                                unsigned short* __restrict__ Kb,
                                                unsigned short* __restrict__ Vt) {
  __shared__ unsigned short lds[16384];                  // 32 KB: As|Bs during GEMM, T after
  unsigned short (*As)[64] = (unsigned short (*)[64])lds;
  unsigned short (*Bs)[64] = (unsigned short (*)[64])(lds + 8192);
  const int xcd = blockIdx.x & 7, u = blockIdx.x >> 3;   // u 0..95
  const int g = xcd * 12 + (u >> 3);                     // unit 0..95
  const int z = g >> 5, mstrip = g & 31;
  const int m0 = mstrip * 128, n0 = (u & 7) * 128;

  const unsigned short* A = (z == 0) ? qc : (z == 1) ? kc : vc;
  const unsigned short* Bw = (z == 0) ? Wqb : (z == 1) ? Wkb : Wvb;

  f32x4 acc[4][4] = {};
  gemm_core(A, Bw, m0, n0, acc, As, Bs);

  const int tid = threadIdx.x;
  const int lane = tid & 63, wave = tid >> 6;
  const int wm = wave >> 1, wn = wave & 1;
  const int row16 = lane & 15, kgrp = lane >> 4;

  if (z < 2) {
    unsigned short* C = z ? Kb : Qb;
#pragma unroll
    for (int mi = 0; mi < 4; mi++)
#pragma unroll
      for (int ni = 0; ni < 4; ni++)
#pragma unroll
        for (int r = 0; r < 4; r++) {
          int row = m0 + wm * 64 + mi * 16 + kgrp * 4 + r;
          int col = n0 + wn * 64 + ni * 16 + row16;
          C[(size_t)row * 1024 + col] = f2bu(acc[mi][ni][r]);
        }
  } else {
    // transpose tile via LDS: T[c_loc][m_loc], 256B rows, 16B slots XOR-swizzled by (c_loc&15)
#pragma unroll
    for (int mi = 0; mi < 4; mi++)
#pragma unroll
      for (int ni = 0; ni < 4; ni++) {
        const int m_loc = wm * 64 + mi * 16 + kgrp * 4;
        const int c_loc = wn * 64 + ni * 16 + row16;
        uint2 pk;
        pk.x = cvtpk(acc[mi][ni][0], acc[mi][ni][1]);
        pk.y = cvtpk(acc[mi][ni][2], acc[mi][ni][3]);
        const int slot = (m_loc >> 3) ^ (c_loc & 15);
        *(uint2*)((char*)lds + c_loc * 256 + slot * 16 + ((m_loc >> 2) & 1) * 8) = pk;
      }
    __syncthreads();
    // coalesced Vt stores: 8 iters x (16 lanes x 16B = 256B per dcol row)
    const int bb = m0 >> 11, mb0 = m0 & 2047;
    const int sl = tid & 15;
#pragma unroll
    for (int it = 0; it < 8; it++) {
      const int cr = it * 16 + (tid >> 4);
      const int ps = sl ^ (cr & 15);
      uint4 vv = *(const uint4*)((const char*)lds + cr * 256 + ps * 16);
      *(uint4*)&Vt[(((size_t)(bb * 1024 + n0 + cr)) << 11) + mb0 + sl * 8] = vv;
    }
  }
}

// output projection: out = attn(bf16) * Wo(bf16)^T, f32 out. 1D grid 256, XCD-aware.
__global__ __launch_bounds__(256) void gemm_wo(const unsigned short* __restrict__ A,
                                               const unsigned short* __restrict__ Bw,
                                               float* __restrict__ C) {
  __shared__ unsigned short As[128][64];
  __shared__ unsigned short Bs[128][64];
  const int xcd = blockIdx.x & 7, u = blockIdx.x >> 3;   // u 0..31
  const int g = xcd * 4 + (u >> 3);                      // m-strip 0..31
  const int m0 = g * 128, n0 = (u & 7) * 128;

  f32x4 acc[4][4] = {};
  gemm_core(A, Bw, m0, n0, acc, As, Bs);

  const int lane = threadIdx.x & 63, wave = threadIdx.x >> 6;
  const int wm = wave >> 1, wn = wave & 1;
  const int row16 = lane & 15, kgrp = lane >> 4;
#pragma unroll
  for (int mi = 0; mi < 4; mi++)
#pragma unroll
    for (int ni = 0; ni < 4; ni++)
#pragma unroll
      for (int r = 0; r < 4; r++) {
        int row = m0 + wm * 64 + mi * 16 + kgrp * 4 + r;
        int col = n0 + wn * 64 + ni * 16 + row16;
        C[(size_t)row * 1024 + col] = acc[mi][ni][r];
      }
}

// ---------------------------------------------------------------- V column sums from Vt (deterministic)
// Early-exit: vsum[b] is read by flash only for rows qg < fu[b]; if fu[b]==0 nothing reads it.
__global__ __launch_bounds__(256) void reduce_vt(const unsigned short* __restrict__ Vt,
                                                 const int* __restrict__ fu,
                                                 float* __restrict__ vsum) {
  const int b = blockIdx.x >> 10;
  if (fu[b] == 0) return;
  __shared__ float red[256];
  const unsigned short* p = Vt + ((size_t)blockIdx.x << 11) + threadIdx.x * 8;
  uint4 u = *(const uint4*)p;
  float s = b2f((unsigned short)(u.x & 0xffff));
  s += b2f((unsigned short)(u.x >> 16));
  s += b2f((unsigned short)(u.y & 0xffff));
  s += b2f((unsigned short)(u.y >> 16));
  s += b2f((unsigned short)(u.z & 0xffff));
  s += b2f((unsigned short)(u.z >> 16));
  s += b2f((unsigned short)(u.w & 0xffff));
  s += b2f((unsigned short)(u.w >> 16));
  red[threadIdx.x] = s;
  __syncthreads();
  for (int st = 128; st > 0; st >>= 1) {
    if (threadIdx.x < st) red[threadIdx.x] += red[threadIdx.x + st];
    __syncthreads();
  }
  if (threadIdx.x == 0) vsum[blockIdx.x] = red[0];
}

// ---------------------------------------------------------------- flash attention v12: true async pipeline
// v8 + (1) pair-mask staged to LDS (in-loop mask reads no longer pollute vmcnt),
// (2) split K/V staging with counted vmcnt + raw barriers: end-of-iter waits only K(t+1)
// [vmcnt(2)], V(t+1) stays in flight across the barrier; V(t) landed by pre-PV vmcnt(4).
__global__ __launch_bounds__(256) void flash_attn12(const unsigned short* __restrict__ Q,
                                                    const unsigned short* __restrict__ Kp,
                                                    const unsigned short* __restrict__ Vt,
                                                    const unsigned int* __restrict__ pm,
                                                    const int* __restrict__ fu,
                                                    const float* __restrict__ vsum,
                                                    unsigned short* __restrict__ O) {
  const int S = 2048, DM = 1024;
  const int bid = blockIdx.x;                 // 0..1023
  const int qt = 31 - (bid >> 5);             // longest blocks dispatch first
  const int bh = bid & 31;
  const int b = bh >> 4, h = bh & 15;
  const int tid = threadIdx.x, lane = tid & 63, wave = tid >> 6;
  const int row16 = lane & 15, kgrp = lane >> 4;

  __shared__ unsigned short Ks[2][64][64];   // 16 KB, XOR-swizzled 16B slots
  __shared__ unsigned short Vs[2][64][64];   // 16 KB (V^T tile), swizzled
  __shared__ unsigned short Ps[4][16][64];   // 8 KB per-wave P [q][k], swizzled slots
  __shared__ unsigned int pmL[1024];         // 4 KB: this batch's pair-mask (LDS copy)

  const size_t base = ((size_t)b * S) * DM + h * 64;
  const size_t vtb = ((size_t)(b * 1024 + h * 64)) * S;
  const unsigned int* pmb = pm + b * 1024;

  const int srow = lane >> 3;
  const int sslot = (lane & 7) ^ srow;
  const int sw = row16 & 7;

  const int q0 = qt * 64 + wave * 16;
  const int qg = q0 + row16;                 // this lane's q row (lane-local)
  const int nt = qt + 1;

  // prologue issue order: Q frags, pm stage, K0, V0, [K1, V1]
  s16x8 qf0 = *(const s16x8*)&Q[base + (size_t)qg * DM + kgrp * 8];
  s16x8 qf1 = *(const s16x8*)&Q[base + (size_t)qg * DM + 32 + kgrp * 8];

  GLD16(pmb + wave * 256 + lane * 4, (char*)pmL + wave * 1024);  // 4KB pm -> LDS

  auto stageK = [&](int t, int bf) {
    const int kb = t * 64;
#pragma unroll
    for (int c2 = 0; c2 < 2; c2++) {
      const int r = wave * 16 + c2 * 8 + srow;
      GLD16(Kp + base + (size_t)(kb + r) * DM + sslot * 8,
            (char*)&Ks[bf][0][0] + (wave * 2 + c2) * 1024);
    }
  };
  auto stageV = [&](int t, int bf) {
    const int kb = t * 64;
#pragma unroll
    for (int c2 = 0; c2 < 2; c2++) {
      const int r = wave * 16 + c2 * 8 + srow;
      GLD16(Vt + vtb + (size_t)r * S + kb + sslot * 8,
            (char*)&Vs[bf][0][0] + (wave * 2 + c2) * 1024);
    }
  };

  const short ONE = 0x3F80;
  const s16x8 ones8 = {ONE, ONE, ONE, ONE, ONE, ONE, ONE, ONE};

  f32x4 oacc[4] = {};
  f32x4 lacc = {};                           // running sum_k P[qg][k] (4 equal copies)
  float m_run = -1e30f;

  stageK(0, 0); stageV(0, 0);
  if (nt > 1) {
    stageK(1, 1); stageV(1, 1);
    asm volatile("s_waitcnt vmcnt(4)" ::: "memory");   // Q+pm+K0+V0 done; K1/V1 in flight
  } else {
    asm volatile("s_waitcnt vmcnt(0)" ::: "memory");
  }
  __builtin_amdgcn_s_barrier();

  int cur = 0;
  for (int t = 0; t < nt; ++t) {
    const int kb = t * 64;
    const bool more = (t + 1 < nt);
    if (more) { stageK(t + 1, cur ^ 1); stageV(t + 1, cur ^ 1); }

    // AND-masks from LDS (lgkmcnt domain; no vmem pollution)
    uint2 pmv[4];
#pragma unroll
    for (int nf = 0; nf < 4; nf++)
      pmv[nf] = *(const uint2*)&pmL[(kb + nf * 16 + kgrp * 4) >> 1];

    // S^T = K * Q^T, already in log2 domain (Q pre-scaled by 0.125*log2e)
    f32x4 sc[4];
    __builtin_amdgcn_s_setprio(1);
#pragma unroll
    for (int nf = 0; nf < 4; nf++) {
      const int rr = nf * 16 + row16;
      s16x8 k0 = *(const s16x8*)&Ks[cur][rr][(kgrp ^ sw) * 8];
      s16x8 k1 = *(const s16x8*)&Ks[cur][rr][((4 + kgrp) ^ sw) * 8];
      f32x4 a = {};
      a = MFMA16(k0, qf0, a);
      a = MFMA16(k1, qf1, a);
      sc[nf] = a;
    }
    __builtin_amdgcn_s_setprio(0);

    // causal: only the diagonal tile needs it (p underflows to exact 0)
    if (t == nt - 1) {
#pragma unroll
      for (int nf = 0; nf < 4; nf++) {
        const int kbase = kb + nf * 16 + kgrp * 4;
#pragma unroll
        for (int r = 0; r < 4; r++)
          if (kbase + r > qg) sc[nf][r] = -30000.0f;
      }
    }

    // max over this lane's 16 raw scores (max3-shaped tree), then 2 shfl inside defer gate
    float a0 = fmaxf(fmaxf(sc[0][0], sc[0][1]), sc[0][2]);
    float a1 = fmaxf(fmaxf(sc[0][3], sc[1][0]), sc[1][1]);
    float a2 = fmaxf(fmaxf(sc[1][2], sc[1][3]), sc[2][0]);
    float a3 = fmaxf(fmaxf(sc[2][1], sc[2][2]), sc[2][3]);
    float a4 = fmaxf(fmaxf(sc[3][0], sc[3][1]), sc[3][2]);
    float b0 = fmaxf(fmaxf(a0, a1), a2);
    float b1 = fmaxf(fmaxf(a3, a4), sc[3][3]);
    float tmax = fmaxf(b0, b1);

    if (__any(tmax > m_run)) {
      float wmax = fmaxf(tmax, __shfl_xor(tmax, 16));
      wmax = fmaxf(wmax, __shfl_xor(wmax, 32));
      float alpha = __builtin_exp2f(m_run - wmax);
      m_run = wmax;
      lacc[0] *= alpha; lacc[1] *= alpha; lacc[2] *= alpha; lacc[3] *= alpha;
#pragma unroll
      for (int nf2 = 0; nf2 < 4; nf2++)
#pragma unroll
        for (int r = 0; r < 4; r++) oacc[nf2][r] *= alpha;
    }

#pragma unroll
    for (int nf = 0; nf < 4; nf++)
#pragma unroll
      for (int r = 0; r < 4; r++)
        sc[nf][r] = __builtin_exp2f(sc[nf][r] - m_run);

    // P pack via cvt_pk + AND-mask -> XOR-swizzled Ps
#pragma unroll
    for (int nf = 0; nf < 4; nf++) {
      uint2 pk;
      pk.x = cvtpk(sc[nf][0], sc[nf][1]) & pmv[nf].x;
      pk.y = cvtpk(sc[nf][2], sc[nf][3]) & pmv[nf].y;
      const int slot = (nf * 2 + (kgrp >> 1)) ^ sw;
      *(uint2*)((char*)&Ps[wave][row16][0] + slot * 16 + (kgrp & 1) * 8) = pk;
    }
    s16x8 pf0 = *(const s16x8*)((char*)&Ps[wave][row16][0] + (kgrp ^ sw) * 16);
    s16x8 pf1 = *(const s16x8*)((char*)&Ps[wave][row16][0] + ((4 + kgrp) ^ sw) * 16);

    // ensure V(t) landed (it was allowed to stay in flight across the last barrier)
    if (more) asm volatile("s_waitcnt vmcnt(4)" ::: "memory");   // allow K(t+1)+V(t+1)
    else      asm volatile("s_waitcnt vmcnt(0)" ::: "memory");

    // O^T += V^T * P^T; l += 1^T * P^T (row-sum on the matrix pipe; P already masked)
    __builtin_amdgcn_s_setprio(1);
    lacc = MFMA16(ones8, pf0, lacc);
    lacc = MFMA16(ones8, pf1, lacc);
#pragma unroll
    for (int nf2 = 0; nf2 < 4; nf2++) {
      const int rr = nf2 * 16 + row16;
      s16x8 v0 = *(const s16x8*)&Vs[cur][rr][(kgrp ^ sw) * 8];
      s16x8 v1 = *(const s16x8*)&Vs[cur][rr][((4 + kgrp) ^ sw) * 8];
      oacc[nf2] = MFMA16(v0, pf0, oacc[nf2]);
      oacc[nf2] = MFMA16(v1, pf1, oacc[nf2]);
    }
    __builtin_amdgcn_s_setprio(0);

    if (more) {
      asm volatile("s_waitcnt vmcnt(2)" ::: "memory");  // K(t+1) done; V(t+1) stays in flight
      __builtin_amdgcn_s_barrier();
      cur ^= 1;
    }
  }

  // epilogue: lane owns q=qg, d = nf2*16 + kgrp*4 + r -> packed bf16 stores
  const int fub = fu[b];
  const float* vs = vsum + b * DM + h * 64;
  const float rl = 1.0f / lacc[0];
#pragma unroll
  for (int nf2 = 0; nf2 < 4; nf2++) {
    const int d0 = nf2 * 16 + kgrp * 4;
    float v0 = oacc[nf2][0] * rl, v1 = oacc[nf2][1] * rl;
    float v2 = oacc[nf2][2] * rl, v3 = oacc[nf2][3] * rl;
    if (qg < fub) {
      float4 vv = *(const float4*)&vs[d0];
      v0 = vv.x * (1.0f / 2048.0f);
      v1 = vv.y * (1.0f / 2048.0f);
      v2 = vv.z * (1.0f / 2048.0f);
      v3 = vv.w * (1.0f / 2048.0f);
    }
    uint2 pk;
    pk.x = cvtpk(v0, v1);
    pk.y = cvtpk(v2, v3);
    *(uint2*)&O[base + (size_t)qg * DM + d0] = pk;
  }
}

// ---------------------------------------------------------------- launch
extern "C" void kernel_launch(void* const* d_in, const int* in_sizes, int n_in,
                              void* d_out, int out_size, void* d_ws, size_t ws_size,
                              hipStream_t stream) {
  const float* q    = (const float*)d_in[0];
  const float* k    = (const float*)d_in[1];
  const float* v    = (const float*)d_in[2];
  const int*   mask = (const int*)d_in[3];
  const float* Wq   = (const float*)d_in[4];
  const float* Wk   = (const float*)d_in[5];
  const float* Wv   = (const float*)d_in[6];
  const float* Wo   = (const float*)d_in[7];
  float* out = (float*)d_out;
  char* ws = (char*)d_ws;

  unsigned short* Wqb  = (unsigned short*)(ws + (size_t)0);
  unsigned short* Wkb  = (unsigned short*)(ws + ((size_t)2 << 20));
  unsigned short* Wvb  = (unsigned short*)(ws + ((size_t)4 << 20));
  unsigned short* Wob  = (unsigned short*)(ws + ((size_t)6 << 20));
  unsigned short* vc   = (unsigned short*)(ws + ((size_t)8 << 20));   // dead after qkv_gemm
  unsigned short* attn = (unsigned short*)(ws + ((size_t)8 << 20));   // aliases vc
  unsigned short* Qb   = (unsigned short*)(ws + ((size_t)16 << 20));
  unsigned short* Kb   = (unsigned short*)(ws + ((size_t)24 << 20));
  unsigned short* Vt   = (unsigned short*)(ws + ((size_t)32 << 20));
  float* vsum          = (float*)(ws + ((size_t)40 << 20));
  int*   fub           = (int*)(ws + ((size_t)40 << 20) + (64 << 10));
  unsigned int* pm32   = (unsigned int*)(ws + ((size_t)40 << 20) + (68 << 10));
  unsigned short* qc   = (unsigned short*)d_out;                      // d_out as cast scratch
  unsigned short* kc   = (unsigned short*)d_out + 4194304;

  cast_all<<<8194, 256, 0, stream>>>(q, k, v, Wq, Wk, Wv, Wo, mask,
                                     qc, kc, vc, Wqb, Wkb, Wvb, Wob, fub, pm32);

  qkv_gemm<<<768, 256, 0, stream>>>(qc, kc, vc, Wqb, Wkb, Wvb, Qb, Kb, Vt);

  reduce_vt<<<2048, 256, 0, stream>>>(Vt, fub, vsum);

  flash_attn12<<<1024, 256, 0, stream>>>(Qb, Kb, Vt, pm32, fub, vsum, attn);

  gemm_wo<<<256, 256, 0, stream>>>(attn, Wob, out);
}